// Round 3
// baseline (491.415 us; speedup 1.0000x reference)
//
#include <hip/hip_runtime.h>

// ImplicitNet fused MLP, bf16 MFMA, swapped-operand (D = W·X^T), IN-PLACE LDS.
// 512 threads/block (8 waves), 64 points/block, each wave owns 32 output cols.
// Single 64x256 bf16 activation buffer (32 KB): every wave holds its outputs in
// acc registers across the K-loop, so we barrier after reads and write in place.
// -> 4 blocks/CU (wave-capped), target ~100% occupancy.
//
// d_ws: bf16 weights, fragment-major: chunk(ntile,ktile,lane) holds
// W[ntile*16 + (lane&15)][ktile*32 + (lane>>4)*8 + j]. MFMA A-operand.
// Padding: L0 K 51->64, L3 N 253->256, L8 N 257->272. ws >= 1,089,536 B.

typedef __attribute__((ext_vector_type(8))) short bf16x8;
typedef __attribute__((ext_vector_type(4))) float f32x4;

#define PPTS 50000

__device__ __forceinline__ short f2bf(float f) {
    union { float f; unsigned u; } v; v.f = f;
    unsigned r = v.u + 0x7fffu + ((v.u >> 16) & 1u);   // RTNE (finite inputs)
    return (short)(r >> 16);
}

// packed f32x2 -> bf16x2 (RTNE), one VALU op (no builtin on gfx950 -> asm)
__device__ __forceinline__ unsigned cvt_pk_bf16(float lo, float hi) {
    unsigned r;
    asm("v_cvt_pk_bf16_f32 %0, %1, %2" : "=v"(r) : "v"(lo), "v"(hi));
    return r;
}

// softplus(100x)/100 = max(x,0) + ln(1+e)/100, e = exp(-100|x|) in (0,1].
// ln(1+e)/100 ~= e*(A + B*e + C*e^2); cubic fit, |err| <= 2.5e-5 absolute,
// exact as e->0 (no systematic bias). Kills the v_log transcendental.
__device__ __forceinline__ float softplus100(float x) {
    const float A = 6.9314718e-3f, B = -3.11522e-3f, C = 9.8829e-4f;
    float e = __builtin_amdgcn_exp2f(fabsf(x) * -144.26950408889634f); // exp(-100|x|)
    float t = __builtin_fmaf(C, e, B);
    t = __builtin_fmaf(t, e, A);
    return __builtin_fmaf(e, t, fmaxf(x, 0.0f));
}

// LDS tile [64][256] bf16, row stride 512B, XOR swizzle byte^=(row&7)<<4 (G4).
// Swizzle is a multiple of 16 -> preserves 8B/16B alignment.
__device__ __forceinline__ short* xaddr(short* base, int row, int col) {
    int off = ((row << 9) + (col << 1)) ^ ((row & 7) << 4);
    return (short*)((char*)base + off);
}
__device__ __forceinline__ const short* xaddrc(const short* base, int row, int col) {
    int off = ((row << 9) + (col << 1)) ^ ((row & 7) << 4);
    return (const short*)((const char*)base + off);
}

// ---------------- weight prep: f32 row-major -> bf16 fragment-major ----------------
__global__ void prep_kernel(
    const float* __restrict__ W0, const float* __restrict__ W1, const float* __restrict__ W2,
    const float* __restrict__ W3, const float* __restrict__ W4, const float* __restrict__ W5,
    const float* __restrict__ W6, const float* __restrict__ W7, const float* __restrict__ W8,
    short* __restrict__ wbf)
{
    const int gid = blockIdx.x * blockDim.x + threadIdx.x;
    if (gid >= 68096) return;                       // total 16B chunks
    int l, cid; const float* Wsrc;
    if      (gid <  2048) { l = 0; cid = gid;         Wsrc = W0; }
    else if (gid < 10240) { l = 1; cid = gid -  2048; Wsrc = W1; }
    else if (gid < 18432) { l = 2; cid = gid - 10240; Wsrc = W2; }
    else if (gid < 26624) { l = 3; cid = gid - 18432; Wsrc = W3; }
    else if (gid < 34816) { l = 4; cid = gid - 26624; Wsrc = W4; }
    else if (gid < 43008) { l = 5; cid = gid - 34816; Wsrc = W5; }
    else if (gid < 51200) { l = 6; cid = gid - 43008; Wsrc = W6; }
    else if (gid < 59392) { l = 7; cid = gid - 51200; Wsrc = W7; }
    else                  { l = 8; cid = gid - 59392; Wsrc = W8; }
    const int NR   = (l == 3) ? 253 : ((l == 8) ? 257 : 256);
    const int KR   = (l == 0) ? 51 : 256;
    const int klog = (l == 0) ? 1 : 3;              // ktiles = Kpad/32 = 2 or 8
    const int lane  = cid & 63;
    const int tile  = cid >> 6;
    const int ntile = tile >> klog;
    const int ktile = tile & ((1 << klog) - 1);
    const int n  = ntile * 16 + (lane & 15);
    const int k0 = ktile * 32 + ((lane >> 4) << 3);
    bf16x8 v;
#pragma unroll
    for (int j = 0; j < 8; ++j) {
        int k = k0 + j;
        float f = (n < NR && k < KR) ? Wsrc[n * KR + k] : 0.0f;
        v[j] = f2bf(f);
    }
    ((bf16x8*)wbf)[gid] = v;
}

// ------- one hidden layer, IN PLACE: acc = W @ xb^T; barrier; softplus -> xb -------
// MODE 0: normal. MODE 1: layer 3 (N=253, scale 1/sqrt2 for skip).
template<int KSTEPS, int MODE>
__device__ __forceinline__ void layer_fwd(short* xb,
    const bf16x8* __restrict__ wl, const float* __restrict__ bias, int lane, int wid)
{
    const int prow = lane & 15;
    const int kg   = (lane >> 4) << 3;
    const int rb4  = (lane >> 4) << 2;
    f32x4 bv[2];
#pragma unroll
    for (int nii = 0; nii < 2; ++nii) {              // hoisted: hides under MFMA
        const int cb = (wid * 2 + nii) * 16 + rb4;
        if (MODE == 1 && cb == 252) { f32x4 t = {bias[252], 0.f, 0.f, 0.f}; bv[nii] = t; }
        else bv[nii] = *(const f32x4*)(bias + cb);
    }
    f32x4 acc[4][2] = {};
#pragma unroll 2
    for (int ks = 0; ks < KSTEPS; ++ks) {
        bf16x8 a[2], b[4];
#pragma unroll
        for (int nii = 0; nii < 2; ++nii)
            a[nii] = wl[((wid * 2 + nii) * KSTEPS + ks) * 64 + lane];
#pragma unroll
        for (int mi = 0; mi < 4; ++mi)
            b[mi] = *(const bf16x8*)xaddrc(xb, mi * 16 + prow, ks * 32 + kg);
#pragma unroll
        for (int mi = 0; mi < 4; ++mi)
#pragma unroll
            for (int nii = 0; nii < 2; ++nii)
                acc[mi][nii] = __builtin_amdgcn_mfma_f32_16x16x32_bf16(
                    a[nii], b[mi], acc[mi][nii], 0, 0, 0);
    }
    __syncthreads();                                  // all reads of xb complete
#pragma unroll
    for (int nii = 0; nii < 2; ++nii) {
        const int cb = (wid * 2 + nii) * 16 + rb4;
#pragma unroll
        for (int mi = 0; mi < 4; ++mi) {
            float s[4];
#pragma unroll
            for (int r = 0; r < 4; ++r) {
                float v = softplus100(acc[mi][nii][r] + bv[nii][r]);
                if (MODE == 1) v *= 0.70710678f;
                s[r] = v;
            }
            unsigned p01 = cvt_pk_bf16(s[0], s[1]);
            unsigned p23 = cvt_pk_bf16(s[2], s[3]);
            if (MODE == 1 && cb == 252) {
                *xaddr(xb, mi * 16 + prow, 252) = (short)(p01 & 0xffff);
            } else {
                uint2 pk; pk.x = p01; pk.y = p23;
                *(uint2*)xaddr(xb, mi * 16 + prow, cb) = pk;
            }
        }
    }
}

// ---------------- fused network kernel: 64 points, 8 waves, 32 KB LDS --------------
__global__ __launch_bounds__(512, 8) void net_kernel(
    const float* __restrict__ xin, const float* __restrict__ cond,
    const bf16x8* __restrict__ W,
    const float* __restrict__ b0, const float* __restrict__ b1, const float* __restrict__ b2,
    const float* __restrict__ b3, const float* __restrict__ b4, const float* __restrict__ b5,
    const float* __restrict__ b6, const float* __restrict__ b7, const float* __restrict__ b8,
    float* __restrict__ out)
{
    __shared__ short xb[64 * 256];
    const int t    = threadIdx.x;
    const int pt0  = blockIdx.x * 64;
    const int lane = t & 63;
    const int wid  = t >> 6;

    // hoist skip-connection values (used after layer 3)
    float sk[3] = {0.f, 0.f, 0.f};
    if (t < 64) {
#pragma unroll
        for (int c = 0; c < 3; ++c)
            sk[c] = xin[(pt0 + t) * 3 + c] * 0.70710678f;
    }

    // build X0 = [x(3) | cond(48) | zeros(..63)] per point, bf16 into LDS cols 0..63
    {
        const int row   = t >> 3;           // 0..63
        const int c0    = (t & 7) << 3;     // 0..56
        const int point = pt0 + row;
        const int batch = point / PPTS;
        const float* xp = xin + point * 3;
        const float* cp = cond + batch * 48;
        bf16x8 v;
#pragma unroll
        for (int i = 0; i < 8; ++i) {
            int c = c0 + i;
            float f = (c < 3) ? xp[c] : ((c < 51) ? cp[c - 3] : 0.0f);
            v[i] = f2bf(f);
        }
        *(bf16x8*)xaddr(xb, row, c0) = v;
    }
    __syncthreads();

    layer_fwd<2, 0>(xb, W +     0, b0, lane, wid); __syncthreads();
    layer_fwd<8, 0>(xb, W +  2048, b1, lane, wid); __syncthreads();
    layer_fwd<8, 0>(xb, W + 10240, b2, lane, wid); __syncthreads();
    layer_fwd<8, 1>(xb, W + 18432, b3, lane, wid);
    // skip connection: cols 253..255 of layer-4 input = x_in * 1/sqrt2
    if (t < 64) {
#pragma unroll
        for (int c = 0; c < 3; ++c)
            *xaddr(xb, t, 253 + c) = f2bf(sk[c]);
    }
    __syncthreads();
    layer_fwd<8, 0>(xb, W + 26624, b4, lane, wid); __syncthreads();
    layer_fwd<8, 0>(xb, W + 34816, b5, lane, wid); __syncthreads();
    layer_fwd<8, 0>(xb, W + 43008, b6, lane, wid); __syncthreads();
    layer_fwd<8, 0>(xb, W + 51200, b7, lane, wid); __syncthreads();

    // layer 8: N=257 (17 n-tiles), no activation, f32 store. Wave 0 carries tile 16.
    {
        const bf16x8* wl = W + 59392;
        const int prow = lane & 15;
        const int kg   = (lane >> 4) << 3;
        const int rb4  = (lane >> 4) << 2;
        f32x4 acc[4][2] = {};
        f32x4 acc2[4]   = {};
#pragma unroll 2
        for (int ks = 0; ks < 8; ++ks) {
            bf16x8 a[2], b[4];
#pragma unroll
            for (int nii = 0; nii < 2; ++nii)
                a[nii] = wl[((wid * 2 + nii) * 8 + ks) * 64 + lane];
            bf16x8 a2;
            if (wid == 0) a2 = wl[(128 + ks) * 64 + lane];
#pragma unroll
            for (int mi = 0; mi < 4; ++mi)
                b[mi] = *(const bf16x8*)xaddrc(xb, mi * 16 + prow, ks * 32 + kg);
#pragma unroll
            for (int mi = 0; mi < 4; ++mi) {
#pragma unroll
                for (int nii = 0; nii < 2; ++nii)
                    acc[mi][nii] = __builtin_amdgcn_mfma_f32_16x16x32_bf16(
                        a[nii], b[mi], acc[mi][nii], 0, 0, 0);
            }
            if (wid == 0) {
#pragma unroll
                for (int mi = 0; mi < 4; ++mi)
                    acc2[mi] = __builtin_amdgcn_mfma_f32_16x16x32_bf16(
                        a2, b[mi], acc2[mi], 0, 0, 0);
            }
        }
#pragma unroll
        for (int nii = 0; nii < 2; ++nii) {
            const int cb = (wid * 2 + nii) * 16 + rb4;          // <= 252
            const f32x4 bv = *(const f32x4*)(b8 + cb);
#pragma unroll
            for (int mi = 0; mi < 4; ++mi) {
                const int rowoff = (pt0 + mi * 16 + prow) * 257 + cb;
#pragma unroll
                for (int r = 0; r < 4; ++r)
                    out[rowoff + r] = acc[mi][nii][r] + bv[r];
            }
        }
        if (wid == 0 && rb4 == 0) {
            const float blast = b8[256];
#pragma unroll
            for (int mi = 0; mi < 4; ++mi)
                out[(pt0 + mi * 16 + prow) * 257 + 256] = acc2[mi][0] + blast;
        }
    }
}

extern "C" void kernel_launch(void* const* d_in, const int* in_sizes, int n_in,
                              void* d_out, int out_size, void* d_ws, size_t ws_size,
                              hipStream_t stream)
{
    const float* xin  = (const float*)d_in[0];
    const float* cond = (const float*)d_in[1];
    const float* Wp[9]; const float* bp[9];
    for (int l = 0; l < 9; ++l) { Wp[l] = (const float*)d_in[2 + 2 * l]; bp[l] = (const float*)d_in[3 + 2 * l]; }
    short* wbf = (short*)d_ws;   // needs 1,089,536 B

    prep_kernel<<<dim3(266), dim3(256), 0, stream>>>(
        Wp[0], Wp[1], Wp[2], Wp[3], Wp[4], Wp[5], Wp[6], Wp[7], Wp[8], wbf);
    net_kernel<<<dim3(3125), dim3(512), 0, stream>>>(
        xin, cond, (const bf16x8*)wbf,
        bp[0], bp[1], bp[2], bp[3], bp[4], bp[5], bp[6], bp[7], bp[8],
        (float*)d_out);
}

// Round 4
// 305.173 us; speedup vs baseline: 1.6103x; 1.6103x over previous
//
#include <hip/hip_runtime.h>

// ImplicitNet fused MLP, bf16 MFMA, swapped-operand (D = W·X^T), IN-PLACE LDS.
// 512 threads/block (8 waves), 64 points/block, wave owns 32 output features.
// Single 64x256 bf16 activation buffer (32 KB), overwritten in place each layer
// (acc lives in registers across the read->barrier->write sequence).
// __launch_bounds__(512,6): 3 blocks/CU, reg cap ~85 (R3's (512,8) cap=64 spilled).
//
// d_ws: bf16 weights, fragment-major: chunk(ntile,ktile,lane) holds
// W[ntile*16 + (lane&15)][ktile*32 + (lane>>4)*8 + j]. MFMA A-operand.
// Padding: L0 K 51->64, L3 N 253->256, L8 N 257->272. ws >= 1,089,536 B.

typedef __attribute__((ext_vector_type(8))) short bf16x8;
typedef __attribute__((ext_vector_type(4))) float f32x4;

#define PPTS 50000

__device__ __forceinline__ short f2bf(float f) {
    union { float f; unsigned u; } v; v.f = f;
    unsigned r = v.u + 0x7fffu + ((v.u >> 16) & 1u);   // RTNE (finite inputs)
    return (short)(r >> 16);
}

// packed f32x2 -> bf16x2 (RTNE), one VALU op (no builtin on gfx950 -> asm)
__device__ __forceinline__ unsigned cvt_pk_bf16(float lo, float hi) {
    unsigned r;
    asm("v_cvt_pk_bf16_f32 %0, %1, %2" : "=v"(r) : "v"(lo), "v"(hi));
    return r;
}

// softplus(100x)/100 = max(x,0) + ln(1+e)/100, e = exp(-100|x|) in (0,1].
// ln(1+e)/100 ~= e*(A + B*e + C*e^2); |err| <= 2.5e-5, exact as e->0.
__device__ __forceinline__ float softplus100(float x) {
    const float A = 6.9314718e-3f, B = -3.11522e-3f, C = 9.8829e-4f;
    float e = __builtin_amdgcn_exp2f(fabsf(x) * -144.26950408889634f); // exp(-100|x|)
    float t = __builtin_fmaf(C, e, B);
    t = __builtin_fmaf(t, e, A);
    return __builtin_fmaf(e, t, fmaxf(x, 0.0f));
}

// LDS tile [64][256] bf16, row stride 512B.
// Swizzle: byte ^= ((row&7) ^ 5*bit3(row)) << 4. Bits 4-6 (bank bits 2-4) get a
// permutation that differs between rows r and r+8, so lanes l and l+8 (which share
// l&7 and read rows differing by 8) no longer alias the same bank. Bijective
// within each 512B row; multiple of 16 -> preserves 8/16B alignment.
__device__ __forceinline__ int xswz(int row) {
    return (((row & 7) ^ (5 * ((row >> 3) & 1))) << 4);
}
__device__ __forceinline__ short* xaddr(short* base, int row, int col) {
    int off = ((row << 9) + (col << 1)) ^ xswz(row);
    return (short*)((char*)base + off);
}
__device__ __forceinline__ const short* xaddrc(const short* base, int row, int col) {
    int off = ((row << 9) + (col << 1)) ^ xswz(row);
    return (const short*)((const char*)base + off);
}

// ---------------- weight prep: f32 row-major -> bf16 fragment-major ----------------
__global__ void prep_kernel(
    const float* __restrict__ W0, const float* __restrict__ W1, const float* __restrict__ W2,
    const float* __restrict__ W3, const float* __restrict__ W4, const float* __restrict__ W5,
    const float* __restrict__ W6, const float* __restrict__ W7, const float* __restrict__ W8,
    short* __restrict__ wbf)
{
    const int gid = blockIdx.x * blockDim.x + threadIdx.x;
    if (gid >= 68096) return;                       // total 16B chunks
    int l, cid; const float* Wsrc;
    if      (gid <  2048) { l = 0; cid = gid;         Wsrc = W0; }
    else if (gid < 10240) { l = 1; cid = gid -  2048; Wsrc = W1; }
    else if (gid < 18432) { l = 2; cid = gid - 10240; Wsrc = W2; }
    else if (gid < 26624) { l = 3; cid = gid - 18432; Wsrc = W3; }
    else if (gid < 34816) { l = 4; cid = gid - 26624; Wsrc = W4; }
    else if (gid < 43008) { l = 5; cid = gid - 34816; Wsrc = W5; }
    else if (gid < 51200) { l = 6; cid = gid - 43008; Wsrc = W6; }
    else if (gid < 59392) { l = 7; cid = gid - 51200; Wsrc = W7; }
    else                  { l = 8; cid = gid - 59392; Wsrc = W8; }
    const int NR   = (l == 3) ? 253 : ((l == 8) ? 257 : 256);
    const int KR   = (l == 0) ? 51 : 256;
    const int klog = (l == 0) ? 1 : 3;              // ktiles = Kpad/32 = 2 or 8
    const int lane  = cid & 63;
    const int tile  = cid >> 6;
    const int ntile = tile >> klog;
    const int ktile = tile & ((1 << klog) - 1);
    const int n  = ntile * 16 + (lane & 15);
    const int k0 = ktile * 32 + ((lane >> 4) << 3);
    bf16x8 v;
#pragma unroll
    for (int j = 0; j < 8; ++j) {
        int k = k0 + j;
        float f = (n < NR && k < KR) ? Wsrc[n * KR + k] : 0.0f;
        v[j] = f2bf(f);
    }
    ((bf16x8*)wbf)[gid] = v;
}

// ------- one hidden layer, IN PLACE: acc = W @ xb^T; barrier; softplus -> xb -------
// Bias loads AFTER the K-loop (live-range: keep K-loop register set minimal).
// MODE 0: normal. MODE 1: layer 3 (N=253, scale 1/sqrt2 for skip).
template<int KSTEPS, int MODE>
__device__ __forceinline__ void layer_fwd(short* xb,
    const bf16x8* __restrict__ wl, const float* __restrict__ bias, int lane, int wid)
{
    const int prow = lane & 15;
    const int kg   = (lane >> 4) << 3;
    const int rb4  = (lane >> 4) << 2;
    f32x4 acc[4][2] = {};
#pragma unroll 2
    for (int ks = 0; ks < KSTEPS; ++ks) {
        bf16x8 a[2], b[4];
#pragma unroll
        for (int nii = 0; nii < 2; ++nii)
            a[nii] = wl[((wid * 2 + nii) * KSTEPS + ks) * 64 + lane];
#pragma unroll
        for (int mi = 0; mi < 4; ++mi)
            b[mi] = *(const bf16x8*)xaddrc(xb, mi * 16 + prow, ks * 32 + kg);
#pragma unroll
        for (int mi = 0; mi < 4; ++mi)
#pragma unroll
            for (int nii = 0; nii < 2; ++nii)
                acc[mi][nii] = __builtin_amdgcn_mfma_f32_16x16x32_bf16(
                    a[nii], b[mi], acc[mi][nii], 0, 0, 0);
    }
    __syncthreads();                                  // all reads of xb complete
#pragma unroll
    for (int nii = 0; nii < 2; ++nii) {
        const int cb = (wid * 2 + nii) * 16 + rb4;
        f32x4 bv;
        if (MODE == 1 && cb == 252) { f32x4 tb = {bias[252], 0.f, 0.f, 0.f}; bv = tb; }
        else bv = *(const f32x4*)(bias + cb);
#pragma unroll
        for (int mi = 0; mi < 4; ++mi) {
            float s[4];
#pragma unroll
            for (int r = 0; r < 4; ++r) {
                float v = softplus100(acc[mi][nii][r] + bv[r]);
                if (MODE == 1) v *= 0.70710678f;
                s[r] = v;
            }
            unsigned p01 = cvt_pk_bf16(s[0], s[1]);
            unsigned p23 = cvt_pk_bf16(s[2], s[3]);
            if (MODE == 1 && cb == 252) {
                *xaddr(xb, mi * 16 + prow, 252) = (short)(p01 & 0xffff);
            } else {
                uint2 pk; pk.x = p01; pk.y = p23;
                *(uint2*)xaddr(xb, mi * 16 + prow, cb) = pk;
            }
        }
    }
}

// ---------------- fused network kernel: 64 points, 8 waves, 32 KB LDS --------------
__global__ __launch_bounds__(512, 6) void net_kernel(
    const float* __restrict__ xin, const float* __restrict__ cond,
    const bf16x8* __restrict__ W,
    const float* __restrict__ b0, const float* __restrict__ b1, const float* __restrict__ b2,
    const float* __restrict__ b3, const float* __restrict__ b4, const float* __restrict__ b5,
    const float* __restrict__ b6, const float* __restrict__ b7, const float* __restrict__ b8,
    float* __restrict__ out)
{
    __shared__ short xb[64 * 256];
    const int t    = threadIdx.x;
    const int pt0  = blockIdx.x * 64;
    const int lane = t & 63;
    const int wid  = t >> 6;

    // hoist skip-connection values (used after layer 3)
    float sk[3] = {0.f, 0.f, 0.f};
    if (t < 64) {
#pragma unroll
        for (int c = 0; c < 3; ++c)
            sk[c] = xin[(pt0 + t) * 3 + c] * 0.70710678f;
    }

    // build X0 = [x(3) | cond(48) | zeros(..63)] per point, bf16 into LDS cols 0..63
    {
        const int row   = t >> 3;           // 0..63
        const int c0    = (t & 7) << 3;     // 0..56
        const int point = pt0 + row;
        const int batch = point / PPTS;
        const float* xp = xin + point * 3;
        const float* cp = cond + batch * 48;
        bf16x8 v;
#pragma unroll
        for (int i = 0; i < 8; ++i) {
            int c = c0 + i;
            float f = (c < 3) ? xp[c] : ((c < 51) ? cp[c - 3] : 0.0f);
            v[i] = f2bf(f);
        }
        *(bf16x8*)xaddr(xb, row, c0) = v;
    }
    __syncthreads();

    layer_fwd<2, 0>(xb, W +     0, b0, lane, wid); __syncthreads();
    layer_fwd<8, 0>(xb, W +  2048, b1, lane, wid); __syncthreads();
    layer_fwd<8, 0>(xb, W + 10240, b2, lane, wid); __syncthreads();
    layer_fwd<8, 1>(xb, W + 18432, b3, lane, wid);
    // skip connection: cols 253..255 of layer-4 input = x_in * 1/sqrt2
    if (t < 64) {
#pragma unroll
        for (int c = 0; c < 3; ++c)
            *xaddr(xb, t, 253 + c) = f2bf(sk[c]);
    }
    __syncthreads();
    layer_fwd<8, 0>(xb, W + 26624, b4, lane, wid); __syncthreads();
    layer_fwd<8, 0>(xb, W + 34816, b5, lane, wid); __syncthreads();
    layer_fwd<8, 0>(xb, W + 43008, b6, lane, wid); __syncthreads();
    layer_fwd<8, 0>(xb, W + 51200, b7, lane, wid); __syncthreads();

    // layer 8: N=257 (17 n-tiles), no activation, f32 store to d_out.
    // Two m-halves (32 points each) to halve live accumulator registers;
    // wave 0 carries n-tile 16 (only col 256 real).
    {
        const bf16x8* wl = W + 59392;
        const int prow = lane & 15;
        const int kg   = (lane >> 4) << 3;
        const int rb4  = (lane >> 4) << 2;
#pragma unroll
        for (int half = 0; half < 2; ++half) {
            f32x4 acc[2][2] = {};
            f32x4 acc2[2]   = {};
#pragma unroll 2
            for (int ks = 0; ks < 8; ++ks) {
                bf16x8 a[2], b[2], a2;
#pragma unroll
                for (int nii = 0; nii < 2; ++nii)
                    a[nii] = wl[((wid * 2 + nii) * 8 + ks) * 64 + lane];
                if (wid == 0) a2 = wl[(128 + ks) * 64 + lane];
#pragma unroll
                for (int m2 = 0; m2 < 2; ++m2)
                    b[m2] = *(const bf16x8*)xaddrc(xb, (half * 2 + m2) * 16 + prow,
                                                   ks * 32 + kg);
#pragma unroll
                for (int m2 = 0; m2 < 2; ++m2) {
#pragma unroll
                    for (int nii = 0; nii < 2; ++nii)
                        acc[m2][nii] = __builtin_amdgcn_mfma_f32_16x16x32_bf16(
                            a[nii], b[m2], acc[m2][nii], 0, 0, 0);
                }
                if (wid == 0) {
#pragma unroll
                    for (int m2 = 0; m2 < 2; ++m2)
                        acc2[m2] = __builtin_amdgcn_mfma_f32_16x16x32_bf16(
                            a2, b[m2], acc2[m2], 0, 0, 0);
                }
            }
#pragma unroll
            for (int nii = 0; nii < 2; ++nii) {
                const int cb = (wid * 2 + nii) * 16 + rb4;          // <= 252
                const f32x4 bv = *(const f32x4*)(b8 + cb);
#pragma unroll
                for (int m2 = 0; m2 < 2; ++m2) {
                    const int rowoff = (pt0 + (half * 2 + m2) * 16 + prow) * 257 + cb;
#pragma unroll
                    for (int r = 0; r < 4; ++r)
                        out[rowoff + r] = acc[m2][nii][r] + bv[r];
                }
            }
            if (wid == 0 && rb4 == 0) {                              // lanes 0..15
                const float blast = b8[256];
#pragma unroll
                for (int m2 = 0; m2 < 2; ++m2)
                    out[(pt0 + (half * 2 + m2) * 16 + prow) * 257 + 256]
                        = acc2[m2][0] + blast;
            }
        }
    }
}

extern "C" void kernel_launch(void* const* d_in, const int* in_sizes, int n_in,
                              void* d_out, int out_size, void* d_ws, size_t ws_size,
                              hipStream_t stream)
{
    const float* xin  = (const float*)d_in[0];
    const float* cond = (const float*)d_in[1];
    const float* Wp[9]; const float* bp[9];
    for (int l = 0; l < 9; ++l) { Wp[l] = (const float*)d_in[2 + 2 * l]; bp[l] = (const float*)d_in[3 + 2 * l]; }
    short* wbf = (short*)d_ws;   // needs 1,089,536 B

    prep_kernel<<<dim3(266), dim3(256), 0, stream>>>(
        Wp[0], Wp[1], Wp[2], Wp[3], Wp[4], Wp[5], Wp[6], Wp[7], Wp[8], wbf);
    net_kernel<<<dim3(3125), dim3(512), 0, stream>>>(
        xin, cond, (const bf16x8*)wbf,
        bp[0], bp[1], bp[2], bp[3], bp[4], bp[5], bp[6], bp[7], bp[8],
        (float*)d_out);
}